// Round 4
// baseline (137.531 us; speedup 1.0000x reference)
//
#include <hip/hip_runtime.h>

// IDMForwardSim, 3-kernel structure:
//  1) precompute_pack: Wc = W1@W2 packed as bf16 hi/lo MFMA B-fragments (ws)
//  2) matvec_att: att = sigmoid(5*(x@Wc+bc)) via 16x16x32 bf16 MFMA (split),
//     written straight to the att half of d_out
//  3) epilogue_k: IDM math, LDS-FREE: thread=(row,tg) makes every stream
//     (us, att, act) naturally lane-contiguous (28*tid float trick).

#define TT 40
#define DD 128
#define ACT_CLIP 3.5f
#define ATT_TEMP 5.0f

typedef short short8 __attribute__((ext_vector_type(8)));
typedef float f32x4 __attribute__((ext_vector_type(4)));

__device__ __forceinline__ unsigned int bf16_rne(float v) {
    unsigned int u = __float_as_uint(v);
    return (u + 0x7FFFu + ((u >> 16) & 1u)) >> 16;
}

// ---------------------------------------------------------------------------
// Kernel 1: pack Wc (128x48, zero-padded cols 40..47) as MFMA B-fragments.
// Record (s,n,h): s=k-step(0..3), n=n-tile(0..2), h=0 hi/1 lo. 64 lanes x 16B.
// Element j of lane l: k = s*32 + (l>>4)*8 + j ; col = n*16 + (l&15).
// ---------------------------------------------------------------------------
__global__ __launch_bounds__(256) void precompute_pack(
    const float* __restrict__ W1, const float* __restrict__ b1,
    const float* __restrict__ W2, const float* __restrict__ b2,
    unsigned int* __restrict__ wpack,   // 1536 * 16B records
    float* __restrict__ bcp)            // 48 floats
{
    int idx = blockIdx.x * 256 + threadIdx.x;
    if (idx < 1536) {
        int l   = idx & 63;
        int rec = idx >> 6;           // ((s*3+n)*2+h)
        int h   = rec & 1;
        int sn  = rec >> 1;           // s*3+n
        int n   = sn % 3, s = sn / 3;
        int col = n * 16 + (l & 15);
        int k0  = s * 32 + (l >> 4) * 8;
        unsigned short hv[8];
#pragma unroll
        for (int j = 0; j < 8; ++j) {
            float v = 0.0f;
            if (col < TT) {
                int k = k0 + j;
                for (int m = 0; m < 100; ++m)
                    v = fmaf(W1[k * 100 + m], W2[m * TT + col], v);
            }
            unsigned int hi = bf16_rne(v);
            float hif = __uint_as_float(hi << 16);
            unsigned int lo = bf16_rne(v - hif);
            hv[j] = (unsigned short)(h == 0 ? hi : lo);
        }
        uint4 o;
        o.x = hv[0] | ((unsigned)hv[1] << 16);
        o.y = hv[2] | ((unsigned)hv[3] << 16);
        o.z = hv[4] | ((unsigned)hv[5] << 16);
        o.w = hv[6] | ((unsigned)hv[7] << 16);
        reinterpret_cast<uint4*>(wpack)[idx] = o;
    } else if (idx < 1536 + 48) {
        int t = idx - 1536;
        float v = 0.0f;
        if (t < TT) {
            v = b2[t];
            for (int m = 0; m < 100; ++m)
                v = fmaf(b1[m], W2[m * TT + t], v);
        }
        bcp[t] = v;
    }
}

// ---------------------------------------------------------------------------
// Kernel 2: att = sigmoid(5*(x@Wc+bc)). Block 256 = 4 waves, 64 rows/block.
// Wave w: rows w*16..w*16+15. 3 n-tiles x 4 k-steps x 3 split-MFMAs.
// ---------------------------------------------------------------------------
__global__ __launch_bounds__(256, 4) void matvec_att(
    const float* __restrict__ x,
    const unsigned int* __restrict__ wpack,
    const float* __restrict__ bcp,
    float* __restrict__ attout)          // = d_out + B*TT
{
    __shared__ unsigned int swp[6144];   // 24576 B
    __shared__ float sbc[48];
    __shared__ float satt[64 * TT];      // 10240 B

    int tid = threadIdx.x;
    {
        const uint4* src = reinterpret_cast<const uint4*>(wpack);
        uint4* dst = reinterpret_cast<uint4*>(swp);
#pragma unroll
        for (int i = 0; i < 6; ++i) dst[tid + 256 * i] = src[tid + 256 * i];
        if (tid < 48) sbc[tid] = bcp[tid];
    }
    __syncthreads();

    int wave = tid >> 6, lane = tid & 63;
    int l15 = lane & 15, lk = lane >> 4;
    size_t row0 = (size_t)blockIdx.x * 64 + wave * 16 + l15;  // A-row of lane
    const float* xr = x + row0 * DD;

    float4 xv[8];
#pragma unroll
    for (int s = 0; s < 4; ++s) {
        xv[2 * s]     = *reinterpret_cast<const float4*>(xr + s * 32 + lk * 8);
        xv[2 * s + 1] = *reinterpret_cast<const float4*>(xr + s * 32 + lk * 8 + 4);
    }

    f32x4 acc[3] = {f32x4{0,0,0,0}, f32x4{0,0,0,0}, f32x4{0,0,0,0}};

#pragma unroll
    for (int s = 0; s < 4; ++s) {
        float fs[8] = {xv[2*s].x, xv[2*s].y, xv[2*s].z, xv[2*s].w,
                       xv[2*s+1].x, xv[2*s+1].y, xv[2*s+1].z, xv[2*s+1].w};
        union { unsigned int u[4]; short8 v; } ah, al;
#pragma unroll
        for (int p = 0; p < 4; ++p) {
            unsigned int h0 = bf16_rne(fs[2*p]);
            unsigned int h1 = bf16_rne(fs[2*p+1]);
            float f0 = __uint_as_float(h0 << 16);
            float f1 = __uint_as_float(h1 << 16);
            unsigned int l0 = bf16_rne(fs[2*p] - f0);
            unsigned int l1 = bf16_rne(fs[2*p+1] - f1);
            ah.u[p] = h0 | (h1 << 16);
            al.u[p] = l0 | (l1 << 16);
        }
#pragma unroll
        for (int n = 0; n < 3; ++n) {
            int base = (s * 3 + n) * 512;   // uints: 2 records x 256 uints
            short8 bh = *reinterpret_cast<const short8*>(&swp[base + lane * 4]);
            short8 bl = *reinterpret_cast<const short8*>(&swp[base + 256 + lane * 4]);
            acc[n] = __builtin_amdgcn_mfma_f32_16x16x32_bf16(ah.v, bh, acc[n], 0, 0, 0);
            acc[n] = __builtin_amdgcn_mfma_f32_16x16x32_bf16(al.v, bh, acc[n], 0, 0, 0);
            acc[n] = __builtin_amdgcn_mfma_f32_16x16x32_bf16(ah.v, bl, acc[n], 0, 0, 0);
        }
    }

    // C/D: col = lane&15 (+16*n), row = wave*16 + (lane>>4)*4 + reg
#pragma unroll
    for (int n = 0; n < 3; ++n) {
        int col = n * 16 + l15;
        if (col < TT) {
            float bias = sbc[col];
#pragma unroll
            for (int r = 0; r < 4; ++r) {
                int rowl = wave * 16 + lk * 4 + r;
                float L = acc[n][r] + bias;
                satt[rowl * TT + col] =
                    __builtin_amdgcn_rcpf(1.0f + __expf(-ATT_TEMP * L));
            }
        }
    }
    __syncthreads();

    float4* dst = reinterpret_cast<float4*>(attout + (size_t)blockIdx.x * 64 * TT);
    const float4* s4 = reinterpret_cast<const float4*>(satt);
    for (int i = tid; i < 640; i += 256) dst[i] = s4[i];
}

// ---------------------------------------------------------------------------
// Kernel 3: IDM epilogue, LDS-free. thread t0 = blk*320+tid handles
// (row = t0/10, tg = t0%10): us floats [28*t0, 28*t0+28) -- contiguous
// across threads; att/act are float4[t0]. All streams perfectly coalesced.
// __launch_bounds__(320,8): pin VGPR<=64 -> 32 waves/CU.
// ---------------------------------------------------------------------------
__global__ __launch_bounds__(320, 8) void epilogue_k(
    const float* __restrict__ us, const float* __restrict__ prm,
    const float* __restrict__ attg,   // = d_out + B*TT (sigmoided by k2)
    float* __restrict__ act)          // = d_out
{
    unsigned int t0 = blockIdx.x * 320u + threadIdx.x;   // < 2.62M, fits u32

    // ---- us window: 7 contiguous float4 per thread -------------------
    const float4* fv = reinterpret_cast<const float4*>(us) + t0 * 7u;
    float f[28];
#pragma unroll
    for (int q = 0; q < 7; ++q) {
        float4 v = fv[q];
        f[q * 4 + 0] = v.x; f[q * 4 + 1] = v.y;
        f[q * 4 + 2] = v.z; f[q * 4 + 3] = v.w;
    }
    float4 a4 = reinterpret_cast<const float4*>(attg)[t0];
    float av[4] = {a4.x, a4.y, a4.z, a4.w};

    unsigned int row_g = t0 / 10u;                       // magic-mul div
    const float* pr = prm + (size_t)row_g * 5u;
    float desired_v    = pr[0];
    float desired_tgap = pr[1];
    float min_jamx     = pr[2];
    float max_act      = pr[3];
    float min_act      = pr[4];
    float inv_dv = __builtin_amdgcn_rcpf(desired_v);
    float coef   = 0.5f / sqrtf(max_act * min_act);

    float ares[4];
#pragma unroll
    for (int tt = 0; tt < 4; ++tt) {
        float vel = f[tt * 7 + 0];
        float dvl = f[tt * 7 + 2], dxl = f[tt * 7 + 3];
        float dvm = f[tt * 7 + 5], dxm = f[tt * 7 + 6];

        float r  = vel * inv_dv;
        float r2 = r * r;
        float common = 1.0f - r2 * r2;
        float base = fmaf(desired_tgap, vel, min_jamx);
        float gl = fmaf(vel * dvl, coef, base);
        float gm = fmaf(vel * dvm, coef, base);
        float ql = gl * __builtin_amdgcn_rcpf(dxl);
        float qm = gm * __builtin_amdgcn_rcpf(dxm);
        float al = max_act * (common - ql * ql);
        float am = max_act * (common - qm * qm);
        al = fminf(fmaxf(al, -ACT_CLIP), ACT_CLIP);
        am = fminf(fmaxf(am, -ACT_CLIP), ACT_CLIP);
        ares[tt] = fmaf(av[tt], al - am, am);
    }
    reinterpret_cast<float4*>(act)[t0] =
        make_float4(ares[0], ares[1], ares[2], ares[3]);
}

extern "C" void kernel_launch(void* const* d_in, const int* in_sizes, int n_in,
                              void* d_out, int out_size, void* d_ws, size_t ws_size,
                              hipStream_t stream) {
    const float* us  = (const float*)d_in[0];
    const float* prm = (const float*)d_in[1];
    const float* x   = (const float*)d_in[2];
    const float* W1  = (const float*)d_in[3];
    const float* b1  = (const float*)d_in[4];
    const float* W2  = (const float*)d_in[5];
    const float* b2  = (const float*)d_in[6];
    float* out = (float*)d_out;

    int B = in_sizes[1] / 5;                 // 262144

    unsigned int* wpack = (unsigned int*)d_ws;          // 24576 B
    float* bcp = (float*)((char*)d_ws + 24576);         // 192 B

    float* attout = out + (size_t)B * TT;    // att half of d_out (final!)

    hipLaunchKernelGGL(precompute_pack, dim3(7), dim3(256), 0, stream,
                       W1, b1, W2, b2, wpack, bcp);
    hipLaunchKernelGGL(matvec_att, dim3(B / 64), dim3(256), 0, stream,
                       x, wpack, bcp, attout);
    // B*10 threads total, 320/block -> B/32 blocks
    hipLaunchKernelGGL(epilogue_k, dim3(B / 32), dim3(320), 0, stream,
                       us, prm, attout, out);
}